// Round 1
// baseline (7310.394 us; speedup 1.0000x reference)
//
#include <hip/hip_runtime.h>
#include <hip/hip_bf16.h>
#include <math.h>

typedef __attribute__((ext_vector_type(8))) short bf16x8;
typedef __attribute__((ext_vector_type(4))) float f32x4;

#define BM 128
#define BN 128
#define BK 32
#define LDST 56   // padded k-stride: 112B, 16B-aligned, spreads banks

#define EPI_BF16_GELU 0
#define EPI_F32_GELU  1
#define EPI_F32_BIAS  2
#define EPI_HUPD      3

static __device__ __forceinline__ unsigned short f2bf(float f) {
  unsigned int u = __float_as_uint(f);
  u += 0x7FFFu + ((u >> 16) & 1u);   // RNE
  return (unsigned short)(u >> 16);
}
static __device__ __forceinline__ float gelu_f(float x) {
  return 0.5f * x * (1.0f + erff(x * 0.70710678118654752f));
}

union U8 { unsigned short s[8]; bf16x8 v; };

// C[M,N] = act(Acomb[M,K] @ Wt^T + bias), Wt is [N][K] bf16.
// NSRC==0: A is bf16 [M,lda]. NSRC>=1: A = A0 + c1*A1 + c2*A2 + c3*A3 (fp32, shared lda).
template<int NSRC, int EPI>
__global__ __launch_bounds__(256)
void gemm_k(const unsigned short* __restrict__ Ab,
            const float* __restrict__ A0, const float* __restrict__ A1,
            const float* __restrict__ A2, const float* __restrict__ A3,
            float c1, float c2, float c3,
            const unsigned short* __restrict__ Wt,
            const float* __restrict__ bias,
            void* __restrict__ outp,
            const float* __restrict__ hp, const float* __restrict__ q1,
            const float* __restrict__ q2, const float* __restrict__ q3,
            float hs,
            int M, int N, int K, int lda)
{
  __shared__ unsigned short As[2][BM][LDST];
  __shared__ unsigned short Bs[2][BN][LDST];

  const int tid  = threadIdx.x;
  const int lane = tid & 63;
  const int wv   = tid >> 6;
  const int wr   = wv >> 1, wc = wv & 1;     // wave -> 64x64 quadrant
  const int brow = blockIdx.y * BM;
  const int bcol = blockIdx.x * BN;
  const int KT   = K >> 5;
  const int l15  = lane & 15;
  const int l4   = lane >> 4;
  const int ar   = tid >> 2;                 // staging row 0..63 (and +64)
  const int ak   = (tid & 3) << 3;           // staging k-offset {0,8,16,24}

  f32x4 acc[4][4];
  const f32x4 zf = {0.f, 0.f, 0.f, 0.f};
#pragma unroll
  for (int m = 0; m < 4; ++m)
#pragma unroll
    for (int n = 0; n < 4; ++n) acc[m][n] = zf;

  bf16x8 ra0, ra1, rb0, rb1;

  auto load_regs = [&](int kt) {
    const int kof = (kt << 5) + ak;
    const int n0 = bcol + ar, n1 = n0 + 64;
    U8 z;
#pragma unroll
    for (int j = 0; j < 8; ++j) z.s[j] = 0;
    rb0 = (n0 < N) ? *(const bf16x8*)(Wt + (size_t)n0 * K + kof) : z.v;
    rb1 = (n1 < N) ? *(const bf16x8*)(Wt + (size_t)n1 * K + kof) : z.v;
    if constexpr (NSRC == 0) {
      ra0 = *(const bf16x8*)(Ab + (size_t)(brow + ar) * lda + kof);
      ra1 = *(const bf16x8*)(Ab + (size_t)(brow + ar + 64) * lda + kof);
    } else {
#pragma unroll
      for (int h2 = 0; h2 < 2; ++h2) {
        const size_t base = (size_t)(brow + ar + h2 * 64) * lda + kof;
        f32x4 u0 = *(const f32x4*)(A0 + base);
        f32x4 u1 = *(const f32x4*)(A0 + base + 4);
        if constexpr (NSRC >= 2) {
          u0 += c1 * *(const f32x4*)(A1 + base);
          u1 += c1 * *(const f32x4*)(A1 + base + 4);
        }
        if constexpr (NSRC >= 3) {
          u0 += c2 * *(const f32x4*)(A2 + base);
          u1 += c2 * *(const f32x4*)(A2 + base + 4);
        }
        if constexpr (NSRC >= 4) {
          u0 += c3 * *(const f32x4*)(A3 + base);
          u1 += c3 * *(const f32x4*)(A3 + base + 4);
        }
        U8 t;
#pragma unroll
        for (int j = 0; j < 4; ++j) { t.s[j] = f2bf(u0[j]); t.s[4 + j] = f2bf(u1[j]); }
        if (h2 == 0) ra0 = t.v; else ra1 = t.v;
      }
    }
  };

  auto write_lds = [&](int buf) {
    *(bf16x8*)&As[buf][ar][ak]      = ra0;
    *(bf16x8*)&As[buf][ar + 64][ak] = ra1;
    *(bf16x8*)&Bs[buf][ar][ak]      = rb0;
    *(bf16x8*)&Bs[buf][ar + 64][ak] = rb1;
  };

  auto compute = [&](int buf) {
    bf16x8 af[4], bg[4];
#pragma unroll
    for (int m = 0; m < 4; ++m)
      af[m] = *(const bf16x8*)&As[buf][wr * 64 + m * 16 + l15][l4 * 8];
#pragma unroll
    for (int n = 0; n < 4; ++n)
      bg[n] = *(const bf16x8*)&Bs[buf][wc * 64 + n * 16 + l15][l4 * 8];
#pragma unroll
    for (int m = 0; m < 4; ++m)
#pragma unroll
      for (int n = 0; n < 4; ++n)
        acc[m][n] = __builtin_amdgcn_mfma_f32_16x16x32_bf16(af[m], bg[n], acc[m][n], 0, 0, 0);
  };

  load_regs(0);
  write_lds(0);
  __syncthreads();
  int buf = 0;
  for (int kt = 0; kt < KT; ++kt) {
    if (kt + 1 < KT) load_regs(kt + 1);   // issue global loads early
    compute(buf);                         // hide latency under MFMA
    if (kt + 1 < KT) write_lds(buf ^ 1);
    __syncthreads();
    buf ^= 1;
  }

  // epilogue: C/D frag layout col=lane&15, row=(lane>>4)*4+reg (m89-verified)
#pragma unroll
  for (int n = 0; n < 4; ++n) {
    const int col = bcol + wc * 64 + n * 16 + l15;
    if (col >= N) continue;
    const float bv = bias[col];
#pragma unroll
    for (int m = 0; m < 4; ++m) {
      const int row0 = brow + wr * 64 + m * 16 + l4 * 4;
#pragma unroll
      for (int r = 0; r < 4; ++r) {
        const size_t idx = (size_t)(row0 + r) * N + col;
        const float a = acc[m][n][r] + bv;
        if constexpr (EPI == EPI_BF16_GELU) {
          ((unsigned short*)outp)[idx] = f2bf(gelu_f(a));
        } else if constexpr (EPI == EPI_F32_GELU) {
          ((float*)outp)[idx] = gelu_f(a);
        } else if constexpr (EPI == EPI_F32_BIAS) {
          ((float*)outp)[idx] = a;
        } else {  // EPI_HUPD: h_new = h + hs*(k1 + 3k2 + 3k3 + k4), k4 from acc
          const float k4 = gelu_f(a);
          ((float*)outp)[idx] = hp[idx] + hs * (q1[idx] + 3.f * q2[idx] + 3.f * q3[idx] + k4);
        }
      }
    }
  }
}

// W [K][N] fp32 -> Wt [N][K] bf16
__global__ void transpose_k(const float* __restrict__ W, unsigned short* __restrict__ Wt,
                            int K, int N) {
  __shared__ float tile[32][33];
  const int n0 = blockIdx.x * 32, k0 = blockIdx.y * 32;
  const int lx = threadIdx.x, ly = threadIdx.y;
#pragma unroll
  for (int r = ly; r < 32; r += 8)
    tile[r][lx] = W[(size_t)(k0 + r) * N + n0 + lx];
  __syncthreads();
#pragma unroll
  for (int r = ly; r < 32; r += 8)
    Wt[(size_t)(n0 + r) * K + k0 + lx] = f2bf(tile[lx][r]);
}

template<int NSRC, int EPI>
static inline void G(hipStream_t st,
                     const void* Ab, const float* A0, const float* A1, const float* A2,
                     const float* A3, float c1, float c2, float c3,
                     const unsigned short* Wt, const float* bias, void* out,
                     const float* hp, const float* q1, const float* q2, const float* q3,
                     float hs, int M, int N, int K, int lda) {
  dim3 grid((N + BN - 1) / BN, M / BM);
  gemm_k<NSRC, EPI><<<grid, dim3(256), 0, st>>>(
      (const unsigned short*)Ab, A0, A1, A2, A3, c1, c2, c3, Wt, bias, out,
      hp, q1, q2, q3, hs, M, N, K, lda);
}

extern "C" void kernel_launch(void* const* d_in, const int* in_sizes, int n_in,
                              void* d_out, int out_size, void* d_ws, size_t ws_size,
                              hipStream_t stream) {
  const float* x   = (const float*)d_in[0];
  const float* Wi  = (const float*)d_in[1];
  const float* bi  = (const float*)d_in[2];
  const float* W1  = (const float*)d_in[3];
  const float* b1  = (const float*)d_in[4];
  const float* W2  = (const float*)d_in[5];
  const float* b2  = (const float*)d_in[6];
  const float* W3  = (const float*)d_in[7];
  const float* b3  = (const float*)d_in[8];
  const float* Wo1 = (const float*)d_in[9];
  const float* bo1 = (const float*)d_in[10];
  const float* Wo2 = (const float*)d_in[11];
  const float* bo2 = (const float*)d_in[12];

  char* ws = (char*)d_ws;
  unsigned short* Wti  = (unsigned short*)(ws + (0ull  << 20));  // [1024][512]
  unsigned short* Wt1  = (unsigned short*)(ws + (1ull  << 20));  // [1024][1024]
  unsigned short* Wt2  = (unsigned short*)(ws + (3ull  << 20));
  unsigned short* Wt3  = (unsigned short*)(ws + (5ull  << 20));
  unsigned short* Wto1 = (unsigned short*)(ws + (7ull  << 20));  // [512][1024]
  unsigned short* Wto2 = (unsigned short*)(ws + (8ull  << 20));  // [64][512]
  float*          h    = (float*)(ws + (9ull  << 20));           // [2048][1024]
  float*          k1   = (float*)(ws + (17ull << 20));
  float*          k2   = (float*)(ws + (25ull << 20));
  float*          k3   = (float*)(ws + (33ull << 20));
  unsigned short* t1   = (unsigned short*)(ws + (41ull << 20));  // bf16 [2048][1024]
  unsigned short* t2   = (unsigned short*)(ws + (45ull << 20));
  unsigned short* o1   = (unsigned short*)(ws + (49ull << 20));  // bf16 [2048][512]

  dim3 tb(32, 8);
  transpose_k<<<dim3(1024 / 32,  512 / 32), tb, 0, stream>>>(Wi,  Wti,  512, 1024);
  transpose_k<<<dim3(1024 / 32, 1024 / 32), tb, 0, stream>>>(W1,  Wt1, 1024, 1024);
  transpose_k<<<dim3(1024 / 32, 1024 / 32), tb, 0, stream>>>(W2,  Wt2, 1024, 1024);
  transpose_k<<<dim3(1024 / 32, 1024 / 32), tb, 0, stream>>>(W3,  Wt3, 1024, 1024);
  transpose_k<<<dim3( 512 / 32, 1024 / 32), tb, 0, stream>>>(Wo1, Wto1, 1024, 512);
  transpose_k<<<dim3(  64 / 32,  512 / 32), tb, 0, stream>>>(Wo2, Wto2,  512,  64);

  const float dt = 1.0f / 15.0f;
  const int M = 2048, H = 1024;

  // h0 = x[:,0,:] @ Wi + bi   (x row stride = S*D_IN = 8192)
  G<1, EPI_F32_BIAS>(stream, nullptr, x, nullptr, nullptr, nullptr, 0, 0, 0,
                     Wti, bi, h, nullptr, nullptr, nullptr, nullptr, 0.f,
                     M, H, 512, 8192);

  for (int s = 0; s < 15; ++s) {
    // k1 = f(h)
    G<1, EPI_BF16_GELU>(stream, nullptr, h, nullptr, nullptr, nullptr, 0, 0, 0,
                        Wt1, b1, t1, nullptr, nullptr, nullptr, nullptr, 0.f, M, H, H, H);
    G<0, EPI_BF16_GELU>(stream, t1, nullptr, nullptr, nullptr, nullptr, 0, 0, 0,
                        Wt2, b2, t2, nullptr, nullptr, nullptr, nullptr, 0.f, M, H, H, H);
    G<0, EPI_F32_GELU >(stream, t2, nullptr, nullptr, nullptr, nullptr, 0, 0, 0,
                        Wt3, b3, k1, nullptr, nullptr, nullptr, nullptr, 0.f, M, H, H, H);
    // k2 = f(h + dt/3 * k1)
    G<2, EPI_BF16_GELU>(stream, nullptr, h, k1, nullptr, nullptr, dt / 3.f, 0, 0,
                        Wt1, b1, t1, nullptr, nullptr, nullptr, nullptr, 0.f, M, H, H, H);
    G<0, EPI_BF16_GELU>(stream, t1, nullptr, nullptr, nullptr, nullptr, 0, 0, 0,
                        Wt2, b2, t2, nullptr, nullptr, nullptr, nullptr, 0.f, M, H, H, H);
    G<0, EPI_F32_GELU >(stream, t2, nullptr, nullptr, nullptr, nullptr, 0, 0, 0,
                        Wt3, b3, k2, nullptr, nullptr, nullptr, nullptr, 0.f, M, H, H, H);
    // k3 = f(h - dt/3 * k1 + dt * k2)
    G<3, EPI_BF16_GELU>(stream, nullptr, h, k1, k2, nullptr, -dt / 3.f, dt, 0,
                        Wt1, b1, t1, nullptr, nullptr, nullptr, nullptr, 0.f, M, H, H, H);
    G<0, EPI_BF16_GELU>(stream, t1, nullptr, nullptr, nullptr, nullptr, 0, 0, 0,
                        Wt2, b2, t2, nullptr, nullptr, nullptr, nullptr, 0.f, M, H, H, H);
    G<0, EPI_F32_GELU >(stream, t2, nullptr, nullptr, nullptr, nullptr, 0, 0, 0,
                        Wt3, b3, k3, nullptr, nullptr, nullptr, nullptr, 0.f, M, H, H, H);
    // k4 = f(h + dt*(k1 - k2 + k3)) ; h += dt/8*(k1+3k2+3k3+k4) fused
    G<4, EPI_BF16_GELU>(stream, nullptr, h, k1, k2, k3, dt, -dt, dt,
                        Wt1, b1, t1, nullptr, nullptr, nullptr, nullptr, 0.f, M, H, H, H);
    G<0, EPI_BF16_GELU>(stream, t1, nullptr, nullptr, nullptr, nullptr, 0, 0, 0,
                        Wt2, b2, t2, nullptr, nullptr, nullptr, nullptr, 0.f, M, H, H, H);
    G<0, EPI_HUPD    >(stream, t2, nullptr, nullptr, nullptr, nullptr, 0, 0, 0,
                        Wt3, b3, h, h, k1, k2, k3, dt / 8.f, M, H, H, H);
  }

  // out = gelu(h @ Wo1 + bo1) @ Wo2 + bo2
  G<1, EPI_BF16_GELU>(stream, nullptr, h, nullptr, nullptr, nullptr, 0, 0, 0,
                      Wto1, bo1, o1, nullptr, nullptr, nullptr, nullptr, 0.f,
                      M, 512, H, H);
  G<0, EPI_F32_BIAS >(stream, o1, nullptr, nullptr, nullptr, nullptr, 0, 0, 0,
                      Wto2, bo2, d_out, nullptr, nullptr, nullptr, nullptr, 0.f,
                      M, 64, 512, 512);
}

// Round 2
// 3754.214 us; speedup vs baseline: 1.9473x; 1.9473x over previous
//
#include <hip/hip_runtime.h>
#include <hip/hip_bf16.h>
#include <math.h>

typedef __attribute__((ext_vector_type(8))) short bf16x8;
typedef __attribute__((ext_vector_type(4))) float f32x4;

#define EPI_T   0  // out bf16 = gelu(acc+b)
#define EPI_H0  1  // out fp32 h = acc+b ; ob2 = bf16(h)
#define EPI_K1  2  // k1=gelu; write k1b; hu = h + dt/8*k1; ob2 = bf16(h + dt/3*k1)
#define EPI_K2  3  // k2=gelu; write k2b; hu += 3dt/8*k2; ob2 = bf16(h - dt/3*k1 + dt*k2)
#define EPI_K3  4  // k3=gelu; hu += 3dt/8*k3; ob2 = bf16(h + dt*(k1-k2+k3))
#define EPI_K4  5  // k4=gelu; h = hu + dt/8*k4 (fp32 out); ob2 = bf16(h)
#define EPI_OUT 6  // out fp32 = acc+b

static __device__ __forceinline__ unsigned short f2bf(float f) {
  unsigned int u = __float_as_uint(f);
  u += 0x7FFFu + ((u >> 16) & 1u);   // RNE
  return (unsigned short)(u >> 16);
}
static __device__ __forceinline__ float bf2f(unsigned short s) {
  return __uint_as_float(((unsigned int)s) << 16);
}
static __device__ __forceinline__ float gelu_f(float x) {
  return 0.5f * x * (1.0f + erff(x * 0.70710678118654752f));
}

typedef __attribute__((address_space(3))) unsigned int lds_u32;
typedef const __attribute__((address_space(1))) unsigned int glb_u32;
static __device__ __forceinline__ void gl_lds16(const unsigned short* g, unsigned short* l) {
  __builtin_amdgcn_global_load_lds((glb_u32*)g, (lds_u32*)l, 16, 0, 0);
}

// C[M,N] = epi(A[M,K](bf16) @ Wt[N,K]^T + bias). BM=128 BN=64 BK=64, 4 waves.
template<int EPI>
__global__ __launch_bounds__(256)
void gemm_k(const unsigned short* __restrict__ A,
            const unsigned short* __restrict__ Wt,
            const float* __restrict__ bias,
            void* __restrict__ outp,
            unsigned short* __restrict__ ob2,
            const float* __restrict__ hF,
            float* __restrict__ huF,
            const unsigned short* __restrict__ k1p,
            const unsigned short* __restrict__ k2p,
            float dt, int N, int K, int nwg)
{
  __shared__ __attribute__((aligned(16))) unsigned short As[2][128][64];
  __shared__ __attribute__((aligned(16))) unsigned short Bs[2][64][64];

  // bijective XCD swizzle (all nwg here are multiples of 8)
  int bid = blockIdx.x;
  const int cpx = nwg >> 3;
  const int wid = (bid & 7) * cpx + (bid >> 3);
  const int nbx = N >> 6;
  const int bx = wid % nbx, by = wid / nbx;
  const int brow = by << 7, bcol = bx << 6;

  const int tid = threadIdx.x;
  const int lane = tid & 63;
  const int wv = tid >> 6;
  const int wr = wv >> 1, wc = wv & 1;       // wave -> 64x32 sub-tile
  const int l15 = lane & 15, l4 = lane >> 4;
  const int lr = lane >> 3;                  // 0..7 (row within 8-row staging group)
  const int sc = (lane & 7) ^ lr;            // inverse-swizzled source chunk
  const int KT = K >> 6;

  f32x4 acc[4][2];
  const f32x4 zf = {0.f, 0.f, 0.f, 0.f};
#pragma unroll
  for (int m = 0; m < 4; ++m)
#pragma unroll
    for (int n = 0; n < 2; ++n) acc[m][n] = zf;

  // LDS(row, c) holds global chunk c ^ (row&7); dest linear, source pre-swizzled.
  auto STAGE = [&](int buf, int kt) {
    const int kof = kt << 6;  // shorts
#pragma unroll
    for (int c = 0; c < 4; ++c) {
      const int r0 = c * 32 + wv * 8;
      gl_lds16(A + (size_t)(brow + r0 + lr) * K + kof + sc * 8, &As[buf][r0][0]);
    }
#pragma unroll
    for (int c = 0; c < 2; ++c) {
      const int r0 = c * 32 + wv * 8;
      gl_lds16(Wt + (size_t)(bcol + r0 + lr) * K + kof + sc * 8, &Bs[buf][r0][0]);
    }
  };

  auto COMP = [&](int buf) {
#pragma unroll
    for (int ks = 0; ks < 2; ++ks) {
      const int cb = ks * 4 + l4;
      const int ch = cb ^ (l15 & 7);   // swizzled read chunk
      bf16x8 af[4], bg[2];
#pragma unroll
      for (int m = 0; m < 4; ++m)
        af[m] = *(const bf16x8*)&As[buf][wr * 64 + m * 16 + l15][ch * 8];
#pragma unroll
      for (int n = 0; n < 2; ++n)
        bg[n] = *(const bf16x8*)&Bs[buf][wc * 32 + n * 16 + l15][ch * 8];
#pragma unroll
      for (int m = 0; m < 4; ++m)
#pragma unroll
        for (int n = 0; n < 2; ++n)
          acc[m][n] = __builtin_amdgcn_mfma_f32_16x16x32_bf16(af[m], bg[n], acc[m][n], 0, 0, 0);
    }
  };

  STAGE(0, 0);
  int b = 0;
  for (int kt = 0; kt < KT; ++kt) {
    __syncthreads();                       // drains vmcnt -> buf b ready; guards buf b^1 reuse
    if (kt + 1 < KT) STAGE(b ^ 1, kt + 1); // prefetch next tile (completes under COMP)
    COMP(b);
    b ^= 1;
  }

  const float dt3 = dt * (1.f / 3.f), dt8 = dt * 0.125f, dt38 = dt * 0.375f;
#pragma unroll
  for (int n = 0; n < 2; ++n) {
    const int col = bcol + wc * 32 + n * 16 + l15;
    const float bv = bias[col];
#pragma unroll
    for (int m = 0; m < 4; ++m) {
      const int r0 = brow + wr * 64 + m * 16 + l4 * 4;
#pragma unroll
      for (int r = 0; r < 4; ++r) {
        const int row = r0 + r;
        const float a = acc[m][n][r] + bv;
        const size_t ix = (size_t)row * N + col;     // out index
        const size_t ih = (size_t)row * 1024 + col;  // aux index (N==1024 EPIs only)
        if constexpr (EPI == EPI_T) {
          ((unsigned short*)outp)[ix] = f2bf(gelu_f(a));
        } else if constexpr (EPI == EPI_H0) {
          ((float*)outp)[ix] = a;
          ob2[ix] = f2bf(a);
        } else if constexpr (EPI == EPI_K1) {
          const float k1 = gelu_f(a);
          const float h = hF[ih];
          ((unsigned short*)outp)[ih] = f2bf(k1);
          huF[ih] = h + dt8 * k1;
          ob2[ih] = f2bf(h + dt3 * k1);
        } else if constexpr (EPI == EPI_K2) {
          const float k2 = gelu_f(a);
          const float h = hF[ih];
          const float k1 = bf2f(k1p[ih]);
          ((unsigned short*)outp)[ih] = f2bf(k2);
          huF[ih] += dt38 * k2;
          ob2[ih] = f2bf(h - dt3 * k1 + dt * k2);
        } else if constexpr (EPI == EPI_K3) {
          const float k3 = gelu_f(a);
          const float h = hF[ih];
          const float k1 = bf2f(k1p[ih]);
          const float k2 = bf2f(k2p[ih]);
          huF[ih] += dt38 * k3;
          ob2[ih] = f2bf(h + dt * (k1 - k2 + k3));
        } else if constexpr (EPI == EPI_K4) {
          const float k4 = gelu_f(a);
          const float hn = huF[ih] + dt8 * k4;
          ((float*)outp)[ih] = hn;
          ob2[ih] = f2bf(hn);
        } else {  // EPI_OUT
          ((float*)outp)[ix] = a;
        }
      }
    }
  }
}

// W [K][N] fp32 -> Wt [N][K] bf16
__global__ void transpose_k(const float* __restrict__ W, unsigned short* __restrict__ Wt,
                            int K, int N) {
  __shared__ float tile[32][33];
  const int n0 = blockIdx.x * 32, k0 = blockIdx.y * 32;
  const int lx = threadIdx.x, ly = threadIdx.y;
#pragma unroll
  for (int r = ly; r < 32; r += 8)
    tile[r][lx] = W[(size_t)(k0 + r) * N + n0 + lx];
  __syncthreads();
#pragma unroll
  for (int r = ly; r < 32; r += 8)
    Wt[(size_t)(n0 + r) * K + k0 + lx] = f2bf(tile[lx][r]);
}

// x[:,0,:] fp32 [2048][16][512] -> xb bf16 [2048][512]
__global__ void convx_k(const float* __restrict__ x, unsigned short* __restrict__ xb) {
  const int r = blockIdx.x;
  const int c = threadIdx.x << 3;
  const float* s = x + (size_t)r * 8192 + c;
  f32x4 u0 = *(const f32x4*)s;
  f32x4 u1 = *(const f32x4*)(s + 4);
  union { unsigned short q[8]; bf16x8 v; } t;
#pragma unroll
  for (int j = 0; j < 4; ++j) { t.q[j] = f2bf(u0[j]); t.q[4 + j] = f2bf(u1[j]); }
  *(bf16x8*)(xb + (size_t)r * 512 + c) = t.v;
}

template<int EPI>
static inline void G(hipStream_t st, const void* A, const unsigned short* Wt,
                     const float* bias, void* out, void* ob2,
                     const float* hF, float* huF,
                     const unsigned short* k1p, const unsigned short* k2p,
                     float dt, int N, int K) {
  const int nwg = (2048 / 128) * (N / 64);
  gemm_k<EPI><<<nwg, 256, 0, st>>>((const unsigned short*)A, Wt, bias, out,
                                   (unsigned short*)ob2, hF, huF, k1p, k2p, dt, N, K, nwg);
}

extern "C" void kernel_launch(void* const* d_in, const int* in_sizes, int n_in,
                              void* d_out, int out_size, void* d_ws, size_t ws_size,
                              hipStream_t stream) {
  const float* x   = (const float*)d_in[0];
  const float* Wi  = (const float*)d_in[1];
  const float* bi  = (const float*)d_in[2];
  const float* W1  = (const float*)d_in[3];
  const float* b1  = (const float*)d_in[4];
  const float* W2  = (const float*)d_in[5];
  const float* b2  = (const float*)d_in[6];
  const float* W3  = (const float*)d_in[7];
  const float* b3  = (const float*)d_in[8];
  const float* Wo1 = (const float*)d_in[9];
  const float* bo1 = (const float*)d_in[10];
  const float* Wo2 = (const float*)d_in[11];
  const float* bo2 = (const float*)d_in[12];

  char* ws = (char*)d_ws;
  unsigned short* Wti  = (unsigned short*)(ws + (0ull  << 20));  // [1024][512]
  unsigned short* Wt1  = (unsigned short*)(ws + (1ull  << 20));  // [1024][1024]
  unsigned short* Wt2  = (unsigned short*)(ws + (3ull  << 20));
  unsigned short* Wt3  = (unsigned short*)(ws + (5ull  << 20));
  unsigned short* Wto1 = (unsigned short*)(ws + (7ull  << 20));  // [512][1024]
  unsigned short* Wto2 = (unsigned short*)(ws + (8ull  << 20));  // [64][512]
  float*          h    = (float*)(ws + (9ull  << 20));           // fp32 [2048][1024]
  float*          hu   = (float*)(ws + (17ull << 20));           // fp32 [2048][1024]
  unsigned short* xb   = (unsigned short*)hu;                    // alias: xb dead before hu live
  unsigned short* k1b  = (unsigned short*)(ws + (25ull << 20));  // bf16 [2048][1024]
  unsigned short* o1b  = k1b;                                    // alias: k1b dead before o1b live
  unsigned short* k2b  = (unsigned short*)(ws + (29ull << 20));
  unsigned short* t1b  = (unsigned short*)(ws + (33ull << 20));
  unsigned short* t2b  = (unsigned short*)(ws + (37ull << 20));
  unsigned short* cA   = (unsigned short*)(ws + (41ull << 20));  // combo A input
  unsigned short* hb   = (unsigned short*)(ws + (45ull << 20));  // bf16(h)

  dim3 tb(32, 8);
  transpose_k<<<dim3(1024 / 32,  512 / 32), tb, 0, stream>>>(Wi,  Wti,  512, 1024);
  transpose_k<<<dim3(1024 / 32, 1024 / 32), tb, 0, stream>>>(W1,  Wt1, 1024, 1024);
  transpose_k<<<dim3(1024 / 32, 1024 / 32), tb, 0, stream>>>(W2,  Wt2, 1024, 1024);
  transpose_k<<<dim3(1024 / 32, 1024 / 32), tb, 0, stream>>>(W3,  Wt3, 1024, 1024);
  transpose_k<<<dim3( 512 / 32, 1024 / 32), tb, 0, stream>>>(Wo1, Wto1, 1024, 512);
  transpose_k<<<dim3(  64 / 32,  512 / 32), tb, 0, stream>>>(Wo2, Wto2,  512,  64);
  convx_k<<<2048, 64, 0, stream>>>(x, xb);

  const float dt = 1.0f / 15.0f;

  // h0 = x0 @ Wi + bi  (fp32 h + bf16 hb)
  G<EPI_H0>(stream, xb, Wti, bi, h, hb, nullptr, nullptr, nullptr, nullptr, dt, 1024, 512);

  for (int s = 0; s < 15; ++s) {
    // k1 = f(h)
    G<EPI_T >(stream, hb,  Wt1, b1, t1b, nullptr, nullptr, nullptr, nullptr, nullptr, dt, 1024, 1024);
    G<EPI_T >(stream, t1b, Wt2, b2, t2b, nullptr, nullptr, nullptr, nullptr, nullptr, dt, 1024, 1024);
    G<EPI_K1>(stream, t2b, Wt3, b3, k1b, cA, h, hu, nullptr, nullptr, dt, 1024, 1024);
    // k2 = f(h + dt/3 k1)
    G<EPI_T >(stream, cA,  Wt1, b1, t1b, nullptr, nullptr, nullptr, nullptr, nullptr, dt, 1024, 1024);
    G<EPI_T >(stream, t1b, Wt2, b2, t2b, nullptr, nullptr, nullptr, nullptr, nullptr, dt, 1024, 1024);
    G<EPI_K2>(stream, t2b, Wt3, b3, k2b, cA, h, hu, k1b, nullptr, dt, 1024, 1024);
    // k3 = f(h - dt/3 k1 + dt k2)
    G<EPI_T >(stream, cA,  Wt1, b1, t1b, nullptr, nullptr, nullptr, nullptr, nullptr, dt, 1024, 1024);
    G<EPI_T >(stream, t1b, Wt2, b2, t2b, nullptr, nullptr, nullptr, nullptr, nullptr, dt, 1024, 1024);
    G<EPI_K3>(stream, t2b, Wt3, b3, nullptr, cA, h, hu, k1b, k2b, dt, 1024, 1024);
    // k4 = f(h + dt(k1-k2+k3)) ; h = hu + dt/8 k4
    G<EPI_T >(stream, cA,  Wt1, b1, t1b, nullptr, nullptr, nullptr, nullptr, nullptr, dt, 1024, 1024);
    G<EPI_T >(stream, t1b, Wt2, b2, t2b, nullptr, nullptr, nullptr, nullptr, nullptr, dt, 1024, 1024);
    G<EPI_K4>(stream, t2b, Wt3, b3, h, hb, nullptr, hu, nullptr, nullptr, dt, 1024, 1024);
  }

  // out = gelu(h @ Wo1 + bo1) @ Wo2 + bo2
  G<EPI_T  >(stream, hb,  Wto1, bo1, o1b, nullptr, nullptr, nullptr, nullptr, nullptr, dt, 512, 1024);
  G<EPI_OUT>(stream, o1b, Wto2, bo2, d_out, nullptr, nullptr, nullptr, nullptr, nullptr, dt, 64, 512);
}